// Round 6
// 343.409 us; speedup vs baseline: 1.0111x; 1.0111x over previous
//
#include <hip/hip_runtime.h>
#include <hip/hip_bf16.h>
#include <math.h>

// ---------------------------------------------------------------------------
// ModelFC_49134425866355 on MI355X (gfx950)
//
// out0[row] = dot(LN(gelu(E@W1+b1))*g+b, W2[:,sel]) + b2[sel]
//           = rstd*(D - mu*Gw) + Bw     (algebraic LN+GEMV fusion)
//
// r14 change vs r11 champion: E is pre-cast to bf16 ONCE (cvt_fin, fused with
// the finalize launch so the conversion's 6144 BW-bound blocks hide the
// serial finalize block). gemm1p's A path becomes an exact mirror of the
// proven bf16 B path: 16B-granule XOR-swizzled global_load_lds, ONE
// ds_read_b128 per fragment, ZERO f32->bf16 casts in the K-loop.
// Rationale (rocprof): gemm1p was MfmaUtil 22% / VALUBusy 45% — the fp32-A
// fragment-read path spent ~as many VALU issue cycles on cvt as on MFMA,
// and 48KB LDS capped occupancy at 30%. Numerics are bit-identical (same
// RNE cast, applied earlier). LDS drops 49152->36864 (4 blocks/CU).
// Ebf (50MB) aliases hpart (dead after own_lnlog).
// 5 kernels: prep_duo | own_lnlog | cvt_fin | gemm1p | out_scores.
// (r19 = r14 resubmitted verbatim: rounds 1-5 all failed at the
// infrastructure level — GPUAcquisitionTimeout x4, container-failed x1 —
// before any measurement.)
// ---------------------------------------------------------------------------

typedef __bf16 bf16_t;
typedef __bf16  bf16x8  __attribute__((ext_vector_type(8)));
typedef float   floatx4 __attribute__((ext_vector_type(4)));

__device__ __forceinline__ float gelu_exact(float x) {
    return 0.5f * x * (1.0f + erff(x * 0.7071067811865475f));
}
// tanh-form gelu via sigmoid; |err|<~1e-3, below bf16 rounding of bulk path.
__device__ __forceinline__ float gelu_fast(float x) {
    const float z = x * (1.0f + 0.044715f * x * x);
    return __fdividef(x, 1.0f + __expf(-1.5957691216f * z));
}

// async global->LDS, 16B per lane; lds base wave-uniform (HW adds lane*16).
// OFFSET ARG STAYS 0 — nonzero immediate is unverified and broke round 5.
__device__ __forceinline__ void gl_lds16(const void* g, void* l) {
    __builtin_amdgcn_global_load_lds(
        (const __attribute__((address_space(1))) void*)g,
        (__attribute__((address_space(3))) void*)l, 16, 0, 0);
}

// ---------------------------------------------------------------------------
// prep_duo: [0,288) tr_w1 (LDS-tiled transpose) | [288,1056) own_h
// ---------------------------------------------------------------------------
__global__ __launch_bounds__(256) void prep_duo(
        const float* __restrict__ E, const float* __restrict__ W1,
        bf16_t* __restrict__ W1t, float* __restrict__ hpart) {
    __shared__ alignas(16) char smemc[16640];   // max(sT 64x65 fp32, sE 6KB)
    const int bid = blockIdx.x;
    const int tid = threadIdx.x;

    if (bid < 288) {                    // ---- tr_w1: 64x64 LDS-tiled transpose
        float* sT = (float*)smemc;      // [64][65]
        const int bk = bid % 12, bn = bid / 12;
        const int k0 = bk * 64, n0 = bn * 64;
        #pragma unroll
        for (int i = 0; i < 16; ++i) {
            const int idx = tid + i * 256;
            const int kk = idx >> 6, nn = idx & 63;
            sT[kk * 65 + nn] = W1[(size_t)(k0 + kk) * 1536 + n0 + nn];
        }
        __syncthreads();
        #pragma unroll
        for (int i = 0; i < 16; ++i) {
            const int idx = tid + i * 256;
            const int nn = idx >> 6, kk = idx & 63;
            W1t[(size_t)(n0 + nn) * 768 + k0 + kk] = (bf16_t)sT[kk * 65 + nn];
        }
    } else {                            // ---- own_h: hpart[kq][512][1536]
        float* sE = (float*)smemc;      // [8][192]
        const int b  = bid - 288;       // 0..767
        const int a  = b & 63;
        const int rest = b >> 6;        // 0..11
        const int by = rest % 3, kq = rest / 3;

        const float* Ebase = E + (size_t)(520 * a) * 768 + kq * 192;
        for (int idx = tid; idx < 1536; idx += 256) {
            const int row = idx / 192, i = idx - row * 192;
            sE[idx] = Ebase[(size_t)row * 768 + i];
        }
        __syncthreads();

        const int c0 = by * 512 + tid * 2;
        const float* w1p = W1 + (size_t)(kq * 192) * 1536 + c0;
        float ax[8] = {}, ay[8] = {};
        for (int k = 0; k < 192; ++k) {
            const float2 w = *(const float2*)(w1p + (size_t)k * 1536);
            #pragma unroll
            for (int j = 0; j < 8; ++j) {
                const float e = sE[j * 192 + k];   // LDS broadcast
                ax[j] += w.x * e;
                ay[j] += w.y * e;
            }
        }
        #pragma unroll
        for (int j = 0; j < 8; ++j)
            *(float2*)(hpart + (size_t)(kq * 512 + a * 8 + j) * 1536 + c0)
                = make_float2(ax[j], ay[j]);
    }
}

// ---------------------------------------------------------------------------
// own_lnlog: per row (512 blocks): h = gelu_exact(sum of 4 k-partials + b1),
// fp32 LN in LDS, then own[row][100] = LNrow @ W2 + b2 (in-block k-split x2).
// ---------------------------------------------------------------------------
__global__ __launch_bounds__(256) void own_lnlog(
        const float* __restrict__ hpart, const float* __restrict__ b1,
        const float* __restrict__ lng,  const float* __restrict__ lnb,
        const float* __restrict__ W2,   const float* __restrict__ b2,
        float* __restrict__ own) {
    __shared__ float srow[1536];
    __shared__ float red8[8];
    __shared__ float redl[128];
    const int row = blockIdx.x, tid = threadIdx.x;
    const int lane = tid & 63, wv = tid >> 6;

    float x[6];
    #pragma unroll
    for (int i = 0; i < 6; ++i) {
        const int c = tid + i * 256;
        x[i] = gelu_exact(hpart[(size_t)row * 1536 + c]
                        + hpart[(size_t)(512 + row) * 1536 + c]
                        + hpart[(size_t)(1024 + row) * 1536 + c]
                        + hpart[(size_t)(1536 + row) * 1536 + c] + b1[c]);
    }
    float s = 0.f;
    #pragma unroll
    for (int i = 0; i < 6; ++i) s += x[i];
    #pragma unroll
    for (int o = 32; o > 0; o >>= 1) s += __shfl_xor(s, o, 64);
    if (lane == 0) red8[wv] = s;
    __syncthreads();
    const float mu = (red8[0] + red8[1] + red8[2] + red8[3]) * (1.0f / 1536.0f);

    float s2 = 0.f;
    #pragma unroll
    for (int i = 0; i < 6; ++i) { float d = x[i] - mu; s2 += d * d; }
    #pragma unroll
    for (int o = 32; o > 0; o >>= 1) s2 += __shfl_xor(s2, o, 64);
    if (lane == 0) red8[4 + wv] = s2;
    __syncthreads();
    const float rstd = rsqrtf((red8[4] + red8[5] + red8[6] + red8[7]) * (1.0f / 1536.0f) + 1e-12f);

    #pragma unroll
    for (int i = 0; i < 6; ++i) {
        const int c = tid + i * 256;
        srow[c] = (x[i] - mu) * rstd * lng[c] + lnb[c];
    }
    __syncthreads();

    // logits for this row: (d, ks) = (128, 2)
    const int d  = tid & 127;
    const int ks = tid >> 7;
    const int dd = d < 100 ? d : 99;
    float acc = ks ? 0.0f : b2[dd];
    const float* hr = srow + ks * 768;
    for (int k = 0; k < 768; ++k)
        acc += hr[k] * W2[(size_t)(ks * 768 + k) * 100 + dd];
    if (ks) redl[d] = acc;
    __syncthreads();
    if (!ks && d < 100) own[(size_t)row * 100 + d] = acc + redl[d];
}

// ---------------------------------------------------------------------------
// cvt_fin: blocks [0,6144): E (fp32) -> Ebf (bf16, RNE — identical rounding
// to the old fragment-read cast, so gemm numerics are bit-identical).
// Block 6144: the old `finalize` — VG_scores / VG_index (fp32-exact,
// first-max), then sel-dependent constants u/Gw/Bw. The 6144 BW-bound cvt
// blocks hide the single serial finalize block.
// ---------------------------------------------------------------------------
__global__ __launch_bounds__(512) void cvt_fin(
        const float* __restrict__ E,   bf16_t* __restrict__ Ebf,
        const float* __restrict__ own, const float* __restrict__ W2,
        const float* __restrict__ b2,  const float* __restrict__ lng,
        const float* __restrict__ lnb, float* __restrict__ out,
        float* __restrict__ u, float* __restrict__ gwbw) {
    __shared__ int ssel;
    __shared__ float rg[8], rb[8];
    const int bid = blockIdx.x;

    if (bid < 6144) {                     // ---- E -> bf16 (25,165,824 elems)
        const size_t base = ((size_t)bid * 512 + threadIdx.x) * 8;
        const float4 v0 = *(const float4*)(E + base);
        const float4 v1 = *(const float4*)(E + base + 4);
        bf16x8 o;
        o[0] = (bf16_t)v0.x; o[1] = (bf16_t)v0.y;
        o[2] = (bf16_t)v0.z; o[3] = (bf16_t)v0.w;
        o[4] = (bf16_t)v1.x; o[5] = (bf16_t)v1.y;
        o[6] = (bf16_t)v1.z; o[7] = (bf16_t)v1.w;
        *(bf16x8*)(Ebf + base) = o;
        return;
    }

    // ---- finalize (one block, 512 threads)
    const int e = threadIdx.x;                    // 0..511
    const int lane = e & 63, wv = e >> 6;
    const float* r = own + (size_t)e * 100;
    float best = r[0]; int bi = 0;
    for (int i = 1; i < 100; ++i) {
        const float v = r[i];
        if (v > best) { best = v; bi = i; }       // strict > keeps first max
    }
    float s = 0.f;
    for (int i = 0; i < 100; ++i) s += expf(r[i] - best);
    out[262144 + e] = 1.0f / s;                   // VG_scores
    out[262656 + e] = (float)bi;                  // VG_scores_index
    if (e == 511) ssel = bi;
    __syncthreads();
    const int sel = ssel;

    float gw = 0.f, bw = 0.f;
    #pragma unroll
    for (int c = e; c < 1536; c += 512) {
        const float wv2 = W2[(size_t)c * 100 + sel];
        const float uu = lng[c] * wv2;
        u[c] = uu;
        gw += uu;
        bw += lnb[c] * wv2;
    }
    #pragma unroll
    for (int o = 32; o > 0; o >>= 1) {
        gw += __shfl_xor(gw, o, 64);
        bw += __shfl_xor(bw, o, 64);
    }
    if (lane == 0) { rg[wv] = gw; rb[wv] = bw; }
    __syncthreads();
    if (e == 0) {
        float G = 0.f, B = 0.f;
        #pragma unroll
        for (int i = 0; i < 8; ++i) { G += rg[i]; B += rb[i]; }
        gwbw[0] = G;
        gwbw[1] = B + b2[sel];
    }
}

// ---------------------------------------------------------------------------
// gemm1p: [32768,768]x[768,1536], 128x128 tile, BK=64, 12 K-tiles.
// BOTH operands bf16, staged via global_load_lds with the 16B-granule XOR
// swizzle (gcol = col ^ (row&7), 8 granules/row): read lanes hit every bank
// exactly 2x (free on gfx950). One ds_read_b128 per fragment, no casts.
// Epilogue: LDS round-trip stats (S1,S2,D). No act matrix.
// ---------------------------------------------------------------------------
__global__ __launch_bounds__(256) void gemm1p(
        const bf16_t* __restrict__ A, const bf16_t* __restrict__ Bt,
        const float* __restrict__ bias, const float* __restrict__ u,
        float* __restrict__ pS1, float* __restrict__ pS2,
        float* __restrict__ pD) {
    constexpr int K = 768;
    __shared__ alignas(16) char smem[36864];   // sA 16KB | sB 16KB; epi 36KB
    bf16_t* sA = (bf16_t*)smem;                // [128][64] bf16, swizzled
    bf16_t* sB = (bf16_t*)(smem + 16384);      // [128][64] bf16, swizzled

    // XCD-aware remap: 12 n-tiles of one m-tile land on one XCD
    const int linear = blockIdx.x + gridDim.x * blockIdx.y;
    const int xcd  = linear & 7;
    const int slot = linear >> 3;
    const int bx = slot % gridDim.x;
    const int by = (slot / gridDim.x) * 8 + xcd;

    const int tid  = threadIdx.x;
    const int lane = tid & 63;
    const int wave = tid >> 6;
    const int wr = wave >> 1, wc = wave & 1;
    const int m0 = by * 128;
    const int n0 = bx * 128;
    const int q  = lane >> 4;
    const int l15 = lane & 15;

    // ---- staging bases (A and B identical structure; 8 granules/row,
    //      swizzle gcol = col ^ (row&7); LDS dest linear, wave-uniform base)
    const bf16_t* gA[4]; bf16_t* lA[4];
    const bf16_t* gB[4]; bf16_t* lB[4];
    #pragma unroll
    for (int c = 0; c < 4; ++c) {
        const int s    = c * 256 + tid;
        const int row  = s >> 3;
        const int col  = s & 7;
        const int gcol = col ^ (row & 7);
        gA[c] = A  + (size_t)(m0 + row) * K + gcol * 8;
        lA[c] = sA + (c * 256 + wave * 64) * 8;
        gB[c] = Bt + (size_t)(n0 + row) * K + gcol * 8;
        lB[c] = sB + (c * 256 + wave * 64) * 8;
    }
    // ---- read bases (K-step invariant); row&7 == lane&7 for both
    const bf16_t* rA[4]; const bf16_t* rB[4];
    #pragma unroll
    for (int t4 = 0; t4 < 4; ++t4) {
        rA[t4] = sA + (wr * 64 + t4 * 16 + l15) * 64;
        rB[t4] = sB + (wc * 64 + t4 * 16 + l15) * 64;
    }
    const int c0 = ((q)     ^ (lane & 7)) * 8;   // ks=0 fragment offset
    const int c1 = ((4 + q) ^ (lane & 7)) * 8;   // ks=1 fragment offset

    floatx4 acc[4][4] = {};

    #pragma unroll
    for (int kt = 0; kt < 12; ++kt) {
        const int k0 = kt * 64;
        __syncthreads();   // prev compute done before LDS overwrite
        #pragma unroll
        for (int c = 0; c < 4; ++c) gl_lds16(gB[c] + k0, lB[c]);
        #pragma unroll
        for (int c = 0; c < 4; ++c) gl_lds16(gA[c] + k0, lA[c]);
        __syncthreads();   // drain DMA, then barrier

        #pragma unroll
        for (int ks = 0; ks < 2; ++ks) {
            const int co = ks ? c1 : c0;
            bf16x8 af[4], bfr[4];
            #pragma unroll
            for (int t4 = 0; t4 < 4; ++t4) {
                af[t4]  = *(const bf16x8*)(rA[t4] + co);
                bfr[t4] = *(const bf16x8*)(rB[t4] + co);
            }
            #pragma unroll
            for (int mt = 0; mt < 4; ++mt)
                #pragma unroll
                for (int nt = 0; nt < 4; ++nt)
                    acc[mt][nt] = __builtin_amdgcn_mfma_f32_16x16x32_bf16(
                        af[mt], bfr[nt], acc[mt][nt], 0, 0, 0);
        }
    }

    // ---- stats epilogue via LDS (low VGPR). C/D layout: col=l15, row=q*4+r.
    __syncthreads();                       // all tile ds_reads done
    bf16_t* sh = (bf16_t*)smem;            // [128][130] bf16 = 33280 B
    float*  su = (float*)(smem + 33280);   // u[n0..n0+127]          512 B
    float*  sp = (float*)(smem + 33792);   // [256][3] partials     3072 B

    if (tid < 128) su[tid] = u[n0 + tid];
    float bias4[4];
    #pragma unroll
    for (int nt = 0; nt < 4; ++nt) bias4[nt] = bias[n0 + wc * 64 + nt * 16 + l15];

    #pragma unroll
    for (int mt = 0; mt < 4; ++mt)
        #pragma unroll
        for (int nt = 0; nt < 4; ++nt)
            #pragma unroll
            for (int r = 0; r < 4; ++r) {
                const int rowl = wr * 64 + mt * 16 + q * 4 + r;
                const int coll = wc * 64 + nt * 16 + l15;
                sh[rowl * 130 + coll] = (bf16_t)gelu_fast(acc[mt][nt][r] + bias4[nt]);
            }
    __syncthreads();

    // phase 2: thread = (row, half); reduce 64 cols each
    {
        const int rowl = tid >> 1, half = tid & 1;
        const bf16_t* hp = sh + rowl * 130 + half * 64;
        const float*  up = su + half * 64;
        float s1 = 0.f, s2 = 0.f, dd = 0.f;
        #pragma unroll
        for (int c = 0; c < 64; ++c) {
            const float v = (float)hp[c];
            s1 += v; s2 += v * v; dd += v * up[c];
        }
        sp[tid * 3 + 0] = s1; sp[tid * 3 + 1] = s2; sp[tid * 3 + 2] = dd;
    }
    __syncthreads();
    if (tid < 128) {
        const float* p0 = sp + (2 * tid) * 3;
        const float* p1 = sp + (2 * tid + 1) * 3;
        const size_t idx = (size_t)bx * 32768 + (m0 + tid);
        pS1[idx] = p0[0] + p1[0];
        pS2[idx] = p0[1] + p1[1];
        pD[idx]  = p0[2] + p1[2];
    }
}

// ---------------------------------------------------------------------------
// out_scores: out[t*8+k] = rstd*(D - mu*Gw) + Bw   (32768 threads)
// ---------------------------------------------------------------------------
__global__ __launch_bounds__(256) void out_scores(
        const float* __restrict__ pS1, const float* __restrict__ pS2,
        const float* __restrict__ pD,  const float* __restrict__ gwbw,
        float* __restrict__ out) {
    const int t = blockIdx.x * 256 + threadIdx.x;   // 32768 exactly
    float s1 = 0.f, s2 = 0.f, d = 0.f;
    #pragma unroll
    for (int nt = 0; nt < 12; ++nt) {
        const size_t idx = (size_t)nt * 32768 + t;
        s1 += pS1[idx]; s2 += pS2[idx]; d += pD[idx];
    }
    const float mu   = s1 * (1.0f / 1536.0f);
    const float var  = s2 * (1.0f / 1536.0f) - mu * mu;
    const float rstd = rsqrtf(var + 1e-12f);
    const float v = rstd * (d - mu * gwbw[0]) + gwbw[1];
    const float4 f = make_float4(v, v, v, v);
    float4* o = (float4*)(out + (size_t)t * 8);
    o[0] = f; o[1] = f;
}

// ---------------------------------------------------------------------------
extern "C" void kernel_launch(void* const* d_in, const int* in_sizes, int n_in,
                              void* d_out, int out_size, void* d_ws, size_t ws_size,
                              hipStream_t stream) {
    const float* E   = (const float*)d_in[0];
    const float* W1  = (const float*)d_in[1];
    const float* b1  = (const float*)d_in[2];
    const float* lng = (const float*)d_in[3];
    const float* lnb = (const float*)d_in[4];
    const float* W2  = (const float*)d_in[5];
    const float* b2  = (const float*)d_in[6];
    float* out = (float*)d_out;

    char* w = (char*)d_ws;
    auto carve = [&](size_t bytes) {
        void* p = (void*)w;
        w += (bytes + 255) & ~(size_t)255;
        return p;
    };
    bf16_t* W1t   = (bf16_t*)carve((size_t)1536 * 768 * 2);    //  2.4 MB
    // Union region: hpart (12.6 MB, dead after own_lnlog) aliased by
    // Ebf (50.3 MB, written by cvt_fin AFTER own_lnlog completes).
    void*   unionr = carve((size_t)32768 * 768 * 2);           // 50.3 MB
    float*  hpart = (float*)unionr;
    bf16_t* Ebf   = (bf16_t*)unionr;
    float*  own   = (float*)carve((size_t)512 * 100 * 4);
    float*  u     = (float*)carve(1536 * 4);
    float*  gwbw  = (float*)carve(256);
    float*  pS1   = (float*)carve((size_t)12 * 32768 * 4);     //  1.6 MB
    float*  pS2   = (float*)carve((size_t)12 * 32768 * 4);
    float*  pD    = (float*)carve((size_t)12 * 32768 * 4);

    // 1) prep: W1 transpose (tiled) + own-row k-partials
    prep_duo<<<1056, 256, 0, stream>>>(E, W1, W1t, hpart);
    // 2) own rows: sum partials + gelu + LN + logits
    own_lnlog<<<512, 256, 0, stream>>>(hpart, b1, lng, lnb, W2, b2, own);
    // 3) E->bf16 (overwrites hpart region) + finalize (sel, u, Gw, Bw)
    cvt_fin<<<6145, 512, 0, stream>>>(E, Ebf, own, W2, b2, lng, lnb, out, u, gwbw);
    // 4) fused GEMM, both operands bf16 via async DMA
    gemm1p<<<dim3(12, 256), 256, 0, stream>>>(Ebf, W1t, b1, u, pS1, pS2, pD);
    // 5) combine partials -> output 0
    out_scores<<<128, 256, 0, stream>>>(pS1, pS2, pD, gwbw, out);
}

// Round 8
// 337.071 us; speedup vs baseline: 1.0301x; 1.0188x over previous
//
#include <hip/hip_runtime.h>
#include <hip/hip_bf16.h>
#include <math.h>

// ---------------------------------------------------------------------------
// ModelFC_49134425866355 on MI355X (gfx950)
//
// out0[row] = dot(LN(gelu(E@W1+b1))*g+b, W2[:,sel]) + b2[sel]
//           = rstd*(D - mu*Gw) + Bw     (algebraic LN+GEMV fusion)
//
// r20 change vs r14 (343.4us measured, gemm1p 103.7us):
// The E->bf16 conversion pass (cvt_fin, ~40us serial) is folded into
// prep_duo's grid. This required breaking the Ebf<->hpart alias: Ebf now
// has its own carve, and hpart instead unions with pS1/pS2/pD (hpart dies
// after own_lnlog; pS* first written by gemm1p -> disjoint lifetimes).
// finalize returns to a tiny standalone kernel. Workspace 57.7->65.5 MB.
// Grid: prep_duo = 288 tr_w1 + 768 own_h + 12288 cvt = 13344 blocks; the
// BW-bound cvt blocks overlap the L2/L3-bound compute blocks in one launch.
// gemm1p (bf16 A+B via swizzled global_load_lds, 745 TF) is UNCHANGED this
// round — next lever is the 256^2 8-phase port.
// 5 kernels: prep_duo(+cvt) | own_lnlog | finalize | gemm1p | out_scores.
// (r21 = r20 resubmitted verbatim: round 7 failed with
// GPUAcquisitionTimeout before any measurement.)
// ---------------------------------------------------------------------------

typedef __bf16 bf16_t;
typedef __bf16  bf16x8  __attribute__((ext_vector_type(8)));
typedef float   floatx4 __attribute__((ext_vector_type(4)));

__device__ __forceinline__ float gelu_exact(float x) {
    return 0.5f * x * (1.0f + erff(x * 0.7071067811865475f));
}
// tanh-form gelu via sigmoid; |err|<~1e-3, below bf16 rounding of bulk path.
__device__ __forceinline__ float gelu_fast(float x) {
    const float z = x * (1.0f + 0.044715f * x * x);
    return __fdividef(x, 1.0f + __expf(-1.5957691216f * z));
}

// async global->LDS, 16B per lane; lds base wave-uniform (HW adds lane*16).
// OFFSET ARG STAYS 0 — nonzero immediate is unverified and broke round 5.
__device__ __forceinline__ void gl_lds16(const void* g, void* l) {
    __builtin_amdgcn_global_load_lds(
        (const __attribute__((address_space(1))) void*)g,
        (__attribute__((address_space(3))) void*)l, 16, 0, 0);
}

// ---------------------------------------------------------------------------
// prep_duo: [0,288) tr_w1 | [288,1056) own_h | [1056,13344) E->bf16 cvt
// Compute blocks first so the long-latency work starts immediately; the
// 12288 short BW-bound cvt blocks fill the machine behind them.
// ---------------------------------------------------------------------------
__global__ __launch_bounds__(256) void prep_duo(
        const float* __restrict__ E, const float* __restrict__ W1,
        bf16_t* __restrict__ W1t, float* __restrict__ hpart,
        bf16_t* __restrict__ Ebf) {
    __shared__ alignas(16) char smemc[16640];   // max(sT 64x65 fp32, sE 6KB)
    const int bid = blockIdx.x;
    const int tid = threadIdx.x;

    if (bid >= 1056) {                  // ---- E -> bf16 (25,165,824 elems)
        const int cb = bid - 1056;      // 0..12287
        const size_t base = ((size_t)cb * 256 + tid) * 8;
        const float4 v0 = *(const float4*)(E + base);
        const float4 v1 = *(const float4*)(E + base + 4);
        bf16x8 o;
        o[0] = (bf16_t)v0.x; o[1] = (bf16_t)v0.y;
        o[2] = (bf16_t)v0.z; o[3] = (bf16_t)v0.w;
        o[4] = (bf16_t)v1.x; o[5] = (bf16_t)v1.y;
        o[6] = (bf16_t)v1.z; o[7] = (bf16_t)v1.w;
        *(bf16x8*)(Ebf + base) = o;
        return;
    }

    if (bid < 288) {                    // ---- tr_w1: 64x64 LDS-tiled transpose
        float* sT = (float*)smemc;      // [64][65]
        const int bk = bid % 12, bn = bid / 12;
        const int k0 = bk * 64, n0 = bn * 64;
        #pragma unroll
        for (int i = 0; i < 16; ++i) {
            const int idx = tid + i * 256;
            const int kk = idx >> 6, nn = idx & 63;
            sT[kk * 65 + nn] = W1[(size_t)(k0 + kk) * 1536 + n0 + nn];
        }
        __syncthreads();
        #pragma unroll
        for (int i = 0; i < 16; ++i) {
            const int idx = tid + i * 256;
            const int nn = idx >> 6, kk = idx & 63;
            W1t[(size_t)(n0 + nn) * 768 + k0 + kk] = (bf16_t)sT[kk * 65 + nn];
        }
    } else {                            // ---- own_h: hpart[kq][512][1536]
        float* sE = (float*)smemc;      // [8][192]
        const int b  = bid - 288;       // 0..767
        const int a  = b & 63;
        const int rest = b >> 6;        // 0..11
        const int by = rest % 3, kq = rest / 3;

        const float* Ebase = E + (size_t)(520 * a) * 768 + kq * 192;
        for (int idx = tid; idx < 1536; idx += 256) {
            const int row = idx / 192, i = idx - row * 192;
            sE[idx] = Ebase[(size_t)row * 768 + i];
        }
        __syncthreads();

        const int c0 = by * 512 + tid * 2;
        const float* w1p = W1 + (size_t)(kq * 192) * 1536 + c0;
        float ax[8] = {}, ay[8] = {};
        for (int k = 0; k < 192; ++k) {
            const float2 w = *(const float2*)(w1p + (size_t)k * 1536);
            #pragma unroll
            for (int j = 0; j < 8; ++j) {
                const float e = sE[j * 192 + k];   // LDS broadcast
                ax[j] += w.x * e;
                ay[j] += w.y * e;
            }
        }
        #pragma unroll
        for (int j = 0; j < 8; ++j)
            *(float2*)(hpart + (size_t)(kq * 512 + a * 8 + j) * 1536 + c0)
                = make_float2(ax[j], ay[j]);
    }
}

// ---------------------------------------------------------------------------
// own_lnlog: per row (512 blocks): h = gelu_exact(sum of 4 k-partials + b1),
// fp32 LN in LDS, then own[row][100] = LNrow @ W2 + b2 (in-block k-split x2).
// ---------------------------------------------------------------------------
__global__ __launch_bounds__(256) void own_lnlog(
        const float* __restrict__ hpart, const float* __restrict__ b1,
        const float* __restrict__ lng,  const float* __restrict__ lnb,
        const float* __restrict__ W2,   const float* __restrict__ b2,
        float* __restrict__ own) {
    __shared__ float srow[1536];
    __shared__ float red8[8];
    __shared__ float redl[128];
    const int row = blockIdx.x, tid = threadIdx.x;
    const int lane = tid & 63, wv = tid >> 6;

    float x[6];
    #pragma unroll
    for (int i = 0; i < 6; ++i) {
        const int c = tid + i * 256;
        x[i] = gelu_exact(hpart[(size_t)row * 1536 + c]
                        + hpart[(size_t)(512 + row) * 1536 + c]
                        + hpart[(size_t)(1024 + row) * 1536 + c]
                        + hpart[(size_t)(1536 + row) * 1536 + c] + b1[c]);
    }
    float s = 0.f;
    #pragma unroll
    for (int i = 0; i < 6; ++i) s += x[i];
    #pragma unroll
    for (int o = 32; o > 0; o >>= 1) s += __shfl_xor(s, o, 64);
    if (lane == 0) red8[wv] = s;
    __syncthreads();
    const float mu = (red8[0] + red8[1] + red8[2] + red8[3]) * (1.0f / 1536.0f);

    float s2 = 0.f;
    #pragma unroll
    for (int i = 0; i < 6; ++i) { float d = x[i] - mu; s2 += d * d; }
    #pragma unroll
    for (int o = 32; o > 0; o >>= 1) s2 += __shfl_xor(s2, o, 64);
    if (lane == 0) red8[4 + wv] = s2;
    __syncthreads();
    const float rstd = rsqrtf((red8[4] + red8[5] + red8[6] + red8[7]) * (1.0f / 1536.0f) + 1e-12f);

    #pragma unroll
    for (int i = 0; i < 6; ++i) {
        const int c = tid + i * 256;
        srow[c] = (x[i] - mu) * rstd * lng[c] + lnb[c];
    }
    __syncthreads();

    // logits for this row: (d, ks) = (128, 2)
    const int d  = tid & 127;
    const int ks = tid >> 7;
    const int dd = d < 100 ? d : 99;
    float acc = ks ? 0.0f : b2[dd];
    const float* hr = srow + ks * 768;
    for (int k = 0; k < 768; ++k)
        acc += hr[k] * W2[(size_t)(ks * 768 + k) * 100 + dd];
    if (ks) redl[d] = acc;
    __syncthreads();
    if (!ks && d < 100) own[(size_t)row * 100 + d] = acc + redl[d];
}

// ---------------------------------------------------------------------------
// finalize: VG_scores / VG_index (fp32-exact, first-max), then sel-dependent
// constants: u = g.*W2[:,sel], Gw = sum(u), Bw = sum(b.*W2[:,sel]) + b2[sel].
// ONE block, 512 threads.
// ---------------------------------------------------------------------------
__global__ __launch_bounds__(512) void finalize(
        const float* __restrict__ own, const float* __restrict__ W2,
        const float* __restrict__ b2,  const float* __restrict__ lng,
        const float* __restrict__ lnb, float* __restrict__ out,
        float* __restrict__ u, float* __restrict__ gwbw) {
    __shared__ int ssel;
    __shared__ float rg[8], rb[8];
    const int e = threadIdx.x;                    // 0..511
    const int lane = e & 63, wv = e >> 6;
    const float* r = own + (size_t)e * 100;
    float best = r[0]; int bi = 0;
    for (int i = 1; i < 100; ++i) {
        const float v = r[i];
        if (v > best) { best = v; bi = i; }       // strict > keeps first max
    }
    float s = 0.f;
    for (int i = 0; i < 100; ++i) s += expf(r[i] - best);
    out[262144 + e] = 1.0f / s;                   // VG_scores
    out[262656 + e] = (float)bi;                  // VG_scores_index
    if (e == 511) ssel = bi;
    __syncthreads();
    const int sel = ssel;

    float gw = 0.f, bw = 0.f;
    #pragma unroll
    for (int c = e; c < 1536; c += 512) {
        const float wv2 = W2[(size_t)c * 100 + sel];
        const float uu = lng[c] * wv2;
        u[c] = uu;
        gw += uu;
        bw += lnb[c] * wv2;
    }
    #pragma unroll
    for (int o = 32; o > 0; o >>= 1) {
        gw += __shfl_xor(gw, o, 64);
        bw += __shfl_xor(bw, o, 64);
    }
    if (lane == 0) { rg[wv] = gw; rb[wv] = bw; }
    __syncthreads();
    if (e == 0) {
        float G = 0.f, B = 0.f;
        #pragma unroll
        for (int i = 0; i < 8; ++i) { G += rg[i]; B += rb[i]; }
        gwbw[0] = G;
        gwbw[1] = B + b2[sel];
    }
}

// ---------------------------------------------------------------------------
// gemm1p: [32768,768]x[768,1536], 128x128 tile, BK=64, 12 K-tiles.
// BOTH operands bf16, staged via global_load_lds with the 16B-granule XOR
// swizzle (gcol = col ^ (row&7), 8 granules/row): read lanes hit every bank
// exactly 2x (free on gfx950). One ds_read_b128 per fragment, no casts.
// Epilogue: LDS round-trip stats (S1,S2,D). No act matrix.
// Measured r14: 103.7us, 745 TF, MfmaUtil 33, VALUBusy 50. UNCHANGED.
// ---------------------------------------------------------------------------
__global__ __launch_bounds__(256) void gemm1p(
        const bf16_t* __restrict__ A, const bf16_t* __restrict__ Bt,
        const float* __restrict__ bias, const float* __restrict__ u,
        float* __restrict__ pS1, float* __restrict__ pS2,
        float* __restrict__ pD) {
    constexpr int K = 768;
    __shared__ alignas(16) char smem[36864];   // sA 16KB | sB 16KB; epi 36KB
    bf16_t* sA = (bf16_t*)smem;                // [128][64] bf16, swizzled
    bf16_t* sB = (bf16_t*)(smem + 16384);      // [128][64] bf16, swizzled

    // XCD-aware remap: 12 n-tiles of one m-tile land on one XCD
    const int linear = blockIdx.x + gridDim.x * blockIdx.y;
    const int xcd  = linear & 7;
    const int slot = linear >> 3;
    const int bx = slot % gridDim.x;
    const int by = (slot / gridDim.x) * 8 + xcd;

    const int tid  = threadIdx.x;
    const int lane = tid & 63;
    const int wave = tid >> 6;
    const int wr = wave >> 1, wc = wave & 1;
    const int m0 = by * 128;
    const int n0 = bx * 128;
    const int q  = lane >> 4;
    const int l15 = lane & 15;

    // ---- staging bases (A and B identical structure; 8 granules/row,
    //      swizzle gcol = col ^ (row&7); LDS dest linear, wave-uniform base)
    const bf16_t* gA[4]; bf16_t* lA[4];
    const bf16_t* gB[4]; bf16_t* lB[4];
    #pragma unroll
    for (int c = 0; c < 4; ++c) {
        const int s    = c * 256 + tid;
        const int row  = s >> 3;
        const int col  = s & 7;
        const int gcol = col ^ (row & 7);
        gA[c] = A  + (size_t)(m0 + row) * K + gcol * 8;
        lA[c] = sA + (c * 256 + wave * 64) * 8;
        gB[c] = Bt + (size_t)(n0 + row) * K + gcol * 8;
        lB[c] = sB + (c * 256 + wave * 64) * 8;
    }
    // ---- read bases (K-step invariant); row&7 == lane&7 for both
    const bf16_t* rA[4]; const bf16_t* rB[4];
    #pragma unroll
    for (int t4 = 0; t4 < 4; ++t4) {
        rA[t4] = sA + (wr * 64 + t4 * 16 + l15) * 64;
        rB[t4] = sB + (wc * 64 + t4 * 16 + l15) * 64;
    }
    const int c0 = ((q)     ^ (lane & 7)) * 8;   // ks=0 fragment offset
    const int c1 = ((4 + q) ^ (lane & 7)) * 8;   // ks=1 fragment offset

    floatx4 acc[4][4] = {};

    #pragma unroll
    for (int kt = 0; kt < 12; ++kt) {
        const int k0 = kt * 64;
        __syncthreads();   // prev compute done before LDS overwrite
        #pragma unroll
        for (int c = 0; c < 4; ++c) gl_lds16(gB[c] + k0, lB[c]);
        #pragma unroll
        for (int c = 0; c < 4; ++c) gl_lds16(gA[c] + k0, lA[c]);
        __syncthreads();   // drain DMA, then barrier

        #pragma unroll
        for (int ks = 0; ks < 2; ++ks) {
            const int co = ks ? c1 : c0;
            bf16x8 af[4], bfr[4];
            #pragma unroll
            for (int t4 = 0; t4 < 4; ++t4) {
                af[t4]  = *(const bf16x8*)(rA[t4] + co);
                bfr[t4] = *(const bf16x8*)(rB[t4] + co);
            }
            #pragma unroll
            for (int mt = 0; mt < 4; ++mt)
                #pragma unroll
                for (int nt = 0; nt < 4; ++nt)
                    acc[mt][nt] = __builtin_amdgcn_mfma_f32_16x16x32_bf16(
                        af[mt], bfr[nt], acc[mt][nt], 0, 0, 0);
        }
    }

    // ---- stats epilogue via LDS (low VGPR). C/D layout: col=l15, row=q*4+r.
    __syncthreads();                       // all tile ds_reads done
    bf16_t* sh = (bf16_t*)smem;            // [128][130] bf16 = 33280 B
    float*  su = (float*)(smem + 33280);   // u[n0..n0+127]          512 B
    float*  sp = (float*)(smem + 33792);   // [256][3] partials     3072 B

    if (tid < 128) su[tid] = u[n0 + tid];
    float bias4[4];
    #pragma unroll
    for (int nt = 0; nt < 4; ++nt) bias4[nt] = bias[n0 + wc * 64 + nt * 16 + l15];

    #pragma unroll
    for (int mt = 0; mt < 4; ++mt)
        #pragma unroll
        for (int nt = 0; nt < 4; ++nt)
            #pragma unroll
            for (int r = 0; r < 4; ++r) {
                const int rowl = wr * 64 + mt * 16 + q * 4 + r;
                const int coll = wc * 64 + nt * 16 + l15;
                sh[rowl * 130 + coll] = (bf16_t)gelu_fast(acc[mt][nt][r] + bias4[nt]);
            }
    __syncthreads();

    // phase 2: thread = (row, half); reduce 64 cols each
    {
        const int rowl = tid >> 1, half = tid & 1;
        const bf16_t* hp = sh + rowl * 130 + half * 64;
        const float*  up = su + half * 64;
        float s1 = 0.f, s2 = 0.f, dd = 0.f;
        #pragma unroll
        for (int c = 0; c < 64; ++c) {
            const float v = (float)hp[c];
            s1 += v; s2 += v * v; dd += v * up[c];
        }
        sp[tid * 3 + 0] = s1; sp[tid * 3 + 1] = s2; sp[tid * 3 + 2] = dd;
    }
    __syncthreads();
    if (tid < 128) {
        const float* p0 = sp + (2 * tid) * 3;
        const float* p1 = sp + (2 * tid + 1) * 3;
        const size_t idx = (size_t)bx * 32768 + (m0 + tid);
        pS1[idx] = p0[0] + p1[0];
        pS2[idx] = p0[1] + p1[1];
        pD[idx]  = p0[2] + p1[2];
    }
}

// ---------------------------------------------------------------------------
// out_scores: out[t*8+k] = rstd*(D - mu*Gw) + Bw   (32768 threads)
// ---------------------------------------------------------------------------
__global__ __launch_bounds__(256) void out_scores(
        const float* __restrict__ pS1, const float* __restrict__ pS2,
        const float* __restrict__ pD,  const float* __restrict__ gwbw,
        float* __restrict__ out) {
    const int t = blockIdx.x * 256 + threadIdx.x;   // 32768 exactly
    float s1 = 0.f, s2 = 0.f, d = 0.f;
    #pragma unroll
    for (int nt = 0; nt < 12; ++nt) {
        const size_t idx = (size_t)nt * 32768 + t;
        s1 += pS1[idx]; s2 += pS2[idx]; d += pD[idx];
    }
    const float mu   = s1 * (1.0f / 1536.0f);
    const float var  = s2 * (1.0f / 1536.0f) - mu * mu;
    const float rstd = rsqrtf(var + 1e-12f);
    const float v = rstd * (d - mu * gwbw[0]) + gwbw[1];
    const float4 f = make_float4(v, v, v, v);
    float4* o = (float4*)(out + (size_t)t * 8);
    o[0] = f; o[1] = f;
}

// ---------------------------------------------------------------------------
extern "C" void kernel_launch(void* const* d_in, const int* in_sizes, int n_in,
                              void* d_out, int out_size, void* d_ws, size_t ws_size,
                              hipStream_t stream) {
    const float* E   = (const float*)d_in[0];
    const float* W1  = (const float*)d_in[1];
    const float* b1  = (const float*)d_in[2];
    const float* lng = (const float*)d_in[3];
    const float* lnb = (const float*)d_in[4];
    const float* W2  = (const float*)d_in[5];
    const float* b2  = (const float*)d_in[6];
    float* out = (float*)d_out;

    char* w = (char*)d_ws;
    auto carve = [&](size_t bytes) {
        void* p = (void*)w;
        w += (bytes + 255) & ~(size_t)255;
        return p;
    };
    bf16_t* W1t   = (bf16_t*)carve((size_t)1536 * 768 * 2);    //  2.4 MB
    bf16_t* Ebf   = (bf16_t*)carve((size_t)32768 * 768 * 2);   // 50.3 MB
    float*  own   = (float*)carve((size_t)512 * 100 * 4);
    float*  u     = (float*)carve(1536 * 4);
    float*  gwbw  = (float*)carve(256);
    // Union region: hpart (12.6 MB, written by prep_duo, dead after
    // own_lnlog) overlaps pS1/pS2/pD (4.7 MB, first written by gemm1p,
    // which runs after own_lnlog) — disjoint lifetimes.
    char*   unionr = (char*)carve((size_t)4 * 512 * 1536 * 4); // 12.6 MB
    float*  hpart = (float*)unionr;
    float*  pS1   = (float*)unionr;
    float*  pS2   = (float*)(unionr + (size_t)12 * 32768 * 4);
    float*  pD    = (float*)(unionr + (size_t)24 * 32768 * 4);

    // 1) prep: W1 transpose + own-row k-partials + E->bf16 (fused grid)
    prep_duo<<<13344, 256, 0, stream>>>(E, W1, W1t, hpart, Ebf);
    // 2) own rows: sum partials + gelu + LN + logits
    own_lnlog<<<512, 256, 0, stream>>>(hpart, b1, lng, lnb, W2, b2, own);
    // 3) argmax/softmax -> VG outputs + sel-derived constants u/Gw/Bw
    finalize<<<1, 512, 0, stream>>>(own, W2, b2, lng, lnb, out, u, gwbw);
    // 4) fused GEMM, both operands bf16 via async DMA
    gemm1p<<<dim3(12, 256), 256, 0, stream>>>(Ebf, W1t, b1, u, pS1, pS2, pD);
    // 5) combine partials -> output 0
    out_scores<<<128, 256, 0, stream>>>(pS1, pS2, pD, gwbw, out);
}

// Round 9
// 305.701 us; speedup vs baseline: 1.1358x; 1.1026x over previous
//
#include <hip/hip_runtime.h>
#include <hip/hip_bf16.h>
#include <math.h>

// ---------------------------------------------------------------------------
// ModelFC_49134425866355 on MI355X (gfx950)
//
// out0[row] = dot(LN(gelu(E@W1+b1))*g+b, W2[:,sel]) + b2[sel]
//           = rstd*(D - mu*Gw) + Bw     (algebraic LN+GEMV fusion)
//
// r22 change vs r20 (337.1us measured; gemm1p 102.7us; serial prefix
// prep_duo->own_lnlog->finalize ~225us dominates):
//  * own_lnlog: 512 threads, 4-way k-split GEMV (384 iters/thread, unroll 8),
//    in-block softmax/argmax (wave-0 tournament, exact first-max tie-break),
//    and block 511 computes u/Gw/Bw itself (sel = its own argmax).
//  * finalize kernel ELIMINATED; `own` global buffer eliminated.
//  * tr_w1: W1t stores vectorized to bf16x2.
// gemm1p (bf16 A+B, 745 TF) UNCHANGED for clean attribution.
// 4 kernels: prep_duo(+cvt) | own_lnlog(+fin) | gemm1p | out_scores.
// ---------------------------------------------------------------------------

typedef __bf16 bf16_t;
typedef __bf16  bf16x2  __attribute__((ext_vector_type(2)));
typedef __bf16  bf16x8  __attribute__((ext_vector_type(8)));
typedef float   floatx4 __attribute__((ext_vector_type(4)));

__device__ __forceinline__ float gelu_exact(float x) {
    return 0.5f * x * (1.0f + erff(x * 0.7071067811865475f));
}
// tanh-form gelu via sigmoid; |err|<~1e-3, below bf16 rounding of bulk path.
__device__ __forceinline__ float gelu_fast(float x) {
    const float z = x * (1.0f + 0.044715f * x * x);
    return __fdividef(x, 1.0f + __expf(-1.5957691216f * z));
}

// async global->LDS, 16B per lane; lds base wave-uniform (HW adds lane*16).
// OFFSET ARG STAYS 0 — nonzero immediate is unverified and broke round 5.
__device__ __forceinline__ void gl_lds16(const void* g, void* l) {
    __builtin_amdgcn_global_load_lds(
        (const __attribute__((address_space(1))) void*)g,
        (__attribute__((address_space(3))) void*)l, 16, 0, 0);
}

// ---------------------------------------------------------------------------
// prep_duo: [0,288) tr_w1 | [288,1056) own_h | [1056,13344) E->bf16 cvt
// ---------------------------------------------------------------------------
__global__ __launch_bounds__(256) void prep_duo(
        const float* __restrict__ E, const float* __restrict__ W1,
        bf16_t* __restrict__ W1t, float* __restrict__ hpart,
        bf16_t* __restrict__ Ebf) {
    __shared__ alignas(16) char smemc[16640];   // max(sT 64x65 fp32, sE 6KB)
    const int bid = blockIdx.x;
    const int tid = threadIdx.x;

    if (bid >= 1056) {                  // ---- E -> bf16 (25,165,824 elems)
        const int cb = bid - 1056;      // 0..12287
        const size_t base = ((size_t)cb * 256 + tid) * 8;
        const float4 v0 = *(const float4*)(E + base);
        const float4 v1 = *(const float4*)(E + base + 4);
        bf16x8 o;
        o[0] = (bf16_t)v0.x; o[1] = (bf16_t)v0.y;
        o[2] = (bf16_t)v0.z; o[3] = (bf16_t)v0.w;
        o[4] = (bf16_t)v1.x; o[5] = (bf16_t)v1.y;
        o[6] = (bf16_t)v1.z; o[7] = (bf16_t)v1.w;
        *(bf16x8*)(Ebf + base) = o;
        return;
    }

    if (bid < 288) {                    // ---- tr_w1: 64x64 LDS-tiled transpose
        float* sT = (float*)smemc;      // [64][65]
        const int bk = bid % 12, bn = bid / 12;
        const int k0 = bk * 64, n0 = bn * 64;
        #pragma unroll
        for (int i = 0; i < 16; ++i) {
            const int idx = tid + i * 256;
            const int kk = idx >> 6, nn = idx & 63;
            sT[kk * 65 + nn] = W1[(size_t)(k0 + kk) * 1536 + n0 + nn];
        }
        __syncthreads();
        // vectorized bf16x2 stores: idx covers (nn, kk-pair)
        #pragma unroll
        for (int i = 0; i < 8; ++i) {
            const int idx = tid + i * 256;   // 0..2047
            const int nn = idx >> 5;         // 0..63
            const int kp = (idx & 31) * 2;   // 0,2,..,62
            bf16x2 v;
            v[0] = (bf16_t)sT[kp * 65 + nn];
            v[1] = (bf16_t)sT[(kp + 1) * 65 + nn];
            *(bf16x2*)(W1t + (size_t)(n0 + nn) * 768 + k0 + kp) = v;
        }
    } else {                            // ---- own_h: hpart[kq][512][1536]
        float* sE = (float*)smemc;      // [8][192]
        const int b  = bid - 288;       // 0..767
        const int a  = b & 63;
        const int rest = b >> 6;        // 0..11
        const int by = rest % 3, kq = rest / 3;

        const float* Ebase = E + (size_t)(520 * a) * 768 + kq * 192;
        for (int idx = tid; idx < 1536; idx += 256) {
            const int row = idx / 192, i = idx - row * 192;
            sE[idx] = Ebase[(size_t)row * 768 + i];
        }
        __syncthreads();

        const int c0 = by * 512 + tid * 2;
        const float* w1p = W1 + (size_t)(kq * 192) * 1536 + c0;
        float ax[8] = {}, ay[8] = {};
        for (int k = 0; k < 192; ++k) {
            const float2 w = *(const float2*)(w1p + (size_t)k * 1536);
            #pragma unroll
            for (int j = 0; j < 8; ++j) {
                const float e = sE[j * 192 + k];   // LDS broadcast
                ax[j] += w.x * e;
                ay[j] += w.y * e;
            }
        }
        #pragma unroll
        for (int j = 0; j < 8; ++j)
            *(float2*)(hpart + (size_t)(kq * 512 + a * 8 + j) * 1536 + c0)
                = make_float2(ax[j], ay[j]);
    }
}

// ---------------------------------------------------------------------------
// own_lnlog: per row (512 blocks x 512 threads):
//   h = gelu_exact(sum of 4 k-partials + b1); fp32 LN in LDS;
//   logits[100] via 4-way k-split GEMV; in-block softmax/argmax ->
//   VG_scores / VG_scores_index (exact first-max); block 511 additionally
//   computes sel-derived u / Gw / Bw (sel = its own argmax).
// ---------------------------------------------------------------------------
__global__ __launch_bounds__(512) void own_lnlog(
        const float* __restrict__ hpart, const float* __restrict__ b1,
        const float* __restrict__ lng,  const float* __restrict__ lnb,
        const float* __restrict__ W2,   const float* __restrict__ b2,
        float* __restrict__ out, float* __restrict__ u,
        float* __restrict__ gwbw) {
    __shared__ float srow[1536];
    __shared__ float red16[16];
    __shared__ float redl[384];
    __shared__ float slog[128];
    __shared__ int   ssel;
    const int row = blockIdx.x, tid = threadIdx.x;
    const int lane = tid & 63, wv = tid >> 6;   // wv 0..7

    // ---- gelu(sum of partials + b1), 3 cols/thread
    float x[3];
    #pragma unroll
    for (int i = 0; i < 3; ++i) {
        const int c = tid + i * 512;
        x[i] = gelu_exact(hpart[(size_t)row * 1536 + c]
                        + hpart[(size_t)(512 + row) * 1536 + c]
                        + hpart[(size_t)(1024 + row) * 1536 + c]
                        + hpart[(size_t)(1536 + row) * 1536 + c] + b1[c]);
    }
    float s = x[0] + x[1] + x[2];
    #pragma unroll
    for (int o = 32; o > 0; o >>= 1) s += __shfl_xor(s, o, 64);
    if (lane == 0) red16[wv] = s;
    __syncthreads();
    float mu = 0.f;
    #pragma unroll
    for (int i = 0; i < 8; ++i) mu += red16[i];
    mu *= (1.0f / 1536.0f);

    float s2 = 0.f;
    #pragma unroll
    for (int i = 0; i < 3; ++i) { float d = x[i] - mu; s2 += d * d; }
    #pragma unroll
    for (int o = 32; o > 0; o >>= 1) s2 += __shfl_xor(s2, o, 64);
    if (lane == 0) red16[8 + wv] = s2;
    __syncthreads();
    float v2 = 0.f;
    #pragma unroll
    for (int i = 0; i < 8; ++i) v2 += red16[8 + i];
    const float rstd = rsqrtf(v2 * (1.0f / 1536.0f) + 1e-12f);

    #pragma unroll
    for (int i = 0; i < 3; ++i) {
        const int c = tid + i * 512;
        srow[c] = (x[i] - mu) * rstd * lng[c] + lnb[c];
    }
    __syncthreads();

    // ---- logits: (d, ks) = (128, 4); 384 k-iters each
    const int d  = tid & 127;
    const int ks = tid >> 7;                  // 0..3
    const int dd = d < 100 ? d : 99;
    float acc = (ks == 0) ? b2[dd] : 0.0f;
    const float* hr  = srow + ks * 384;
    const float* w2p = W2 + (size_t)(ks * 384) * 100 + dd;
    #pragma unroll 8
    for (int k = 0; k < 384; ++k)
        acc += hr[k] * w2p[(size_t)k * 100];
    if (ks) redl[(ks - 1) * 128 + d] = acc;
    __syncthreads();
    if (ks == 0) {
        const float tot = acc + redl[d] + redl[128 + d] + redl[256 + d];
        slog[d] = (d < 100) ? tot : -INFINITY;
    }
    __syncthreads();

    // ---- wave 0: softmax max-prob + argmax (first-max tie-break)
    if (wv == 0) {
        const float v0 = slog[lane], v1 = slog[lane + 64];
        float bv; int bi;
        if (v0 >= v1) { bv = v0; bi = lane; } else { bv = v1; bi = lane + 64; }
        #pragma unroll
        for (int o = 1; o < 64; o <<= 1) {
            const float vo = __shfl_xor(bv, o, 64);
            const int   io = __shfl_xor(bi, o, 64);
            if (vo > bv || (vo == bv && io < bi)) { bv = vo; bi = io; }
        }
        float e = expf(v0 - bv) + expf(v1 - bv);   // exp(-inf)=0 pads
        #pragma unroll
        for (int o = 32; o > 0; o >>= 1) e += __shfl_xor(e, o, 64);
        if (lane == 0) {
            out[262144 + row] = 1.0f / e;          // VG_scores
            out[262656 + row] = (float)bi;         // VG_scores_index
            ssel = bi;
        }
    }
    __syncthreads();

    // ---- block 511: sel-derived constants u / Gw / Bw
    if (row == 511) {
        const int sel = ssel;
        float gw = 0.f, bw = 0.f;
        #pragma unroll
        for (int c = tid; c < 1536; c += 512) {
            const float wv2 = W2[(size_t)c * 100 + sel];
            const float uu = lng[c] * wv2;
            u[c] = uu;
            gw += uu;
            bw += lnb[c] * wv2;
        }
        #pragma unroll
        for (int o = 32; o > 0; o >>= 1) {
            gw += __shfl_xor(gw, o, 64);
            bw += __shfl_xor(bw, o, 64);
        }
        if (lane == 0) { red16[wv] = gw; red16[8 + wv] = bw; }
        __syncthreads();
        if (tid == 0) {
            float G = 0.f, B = 0.f;
            #pragma unroll
            for (int i = 0; i < 8; ++i) { G += red16[i]; B += red16[8 + i]; }
            gwbw[0] = G;
            gwbw[1] = B + b2[sel];
        }
    }
}

// ---------------------------------------------------------------------------
// gemm1p: [32768,768]x[768,1536], 128x128 tile, BK=64, 12 K-tiles.
// BOTH operands bf16, staged via global_load_lds with the 16B-granule XOR
// swizzle (gcol = col ^ (row&7), 8 granules/row): read lanes hit every bank
// exactly 2x (free on gfx950). One ds_read_b128 per fragment, no casts.
// Epilogue: LDS round-trip stats (S1,S2,D). No act matrix.
// Measured r20: 102.7us, 745 TF, MfmaUtil 34, VALUBusy 51. UNCHANGED.
// ---------------------------------------------------------------------------
__global__ __launch_bounds__(256) void gemm1p(
        const bf16_t* __restrict__ A, const bf16_t* __restrict__ Bt,
        const float* __restrict__ bias, const float* __restrict__ u,
        float* __restrict__ pS1, float* __restrict__ pS2,
        float* __restrict__ pD) {
    constexpr int K = 768;
    __shared__ alignas(16) char smem[36864];   // sA 16KB | sB 16KB; epi 36KB
    bf16_t* sA = (bf16_t*)smem;                // [128][64] bf16, swizzled
    bf16_t* sB = (bf16_t*)(smem + 16384);      // [128][64] bf16, swizzled

    // XCD-aware remap: 12 n-tiles of one m-tile land on one XCD
    const int linear = blockIdx.x + gridDim.x * blockIdx.y;
    const int xcd  = linear & 7;
    const int slot = linear >> 3;
    const int bx = slot % gridDim.x;
    const int by = (slot / gridDim.x) * 8 + xcd;

    const int tid  = threadIdx.x;
    const int lane = tid & 63;
    const int wave = tid >> 6;
    const int wr = wave >> 1, wc = wave & 1;
    const int m0 = by * 128;
    const int n0 = bx * 128;
    const int q  = lane >> 4;
    const int l15 = lane & 15;

    // ---- staging bases (A and B identical structure; 8 granules/row,
    //      swizzle gcol = col ^ (row&7); LDS dest linear, wave-uniform base)
    const bf16_t* gA[4]; bf16_t* lA[4];
    const bf16_t* gB[4]; bf16_t* lB[4];
    #pragma unroll
    for (int c = 0; c < 4; ++c) {
        const int s    = c * 256 + tid;
        const int row  = s >> 3;
        const int col  = s & 7;
        const int gcol = col ^ (row & 7);
        gA[c] = A  + (size_t)(m0 + row) * K + gcol * 8;
        lA[c] = sA + (c * 256 + wave * 64) * 8;
        gB[c] = Bt + (size_t)(n0 + row) * K + gcol * 8;
        lB[c] = sB + (c * 256 + wave * 64) * 8;
    }
    // ---- read bases (K-step invariant); row&7 == lane&7 for both
    const bf16_t* rA[4]; const bf16_t* rB[4];
    #pragma unroll
    for (int t4 = 0; t4 < 4; ++t4) {
        rA[t4] = sA + (wr * 64 + t4 * 16 + l15) * 64;
        rB[t4] = sB + (wc * 64 + t4 * 16 + l15) * 64;
    }
    const int c0 = ((q)     ^ (lane & 7)) * 8;   // ks=0 fragment offset
    const int c1 = ((4 + q) ^ (lane & 7)) * 8;   // ks=1 fragment offset

    floatx4 acc[4][4] = {};

    #pragma unroll
    for (int kt = 0; kt < 12; ++kt) {
        const int k0 = kt * 64;
        __syncthreads();   // prev compute done before LDS overwrite
        #pragma unroll
        for (int c = 0; c < 4; ++c) gl_lds16(gB[c] + k0, lB[c]);
        #pragma unroll
        for (int c = 0; c < 4; ++c) gl_lds16(gA[c] + k0, lA[c]);
        __syncthreads();   // drain DMA, then barrier

        #pragma unroll
        for (int ks = 0; ks < 2; ++ks) {
            const int co = ks ? c1 : c0;
            bf16x8 af[4], bfr[4];
            #pragma unroll
            for (int t4 = 0; t4 < 4; ++t4) {
                af[t4]  = *(const bf16x8*)(rA[t4] + co);
                bfr[t4] = *(const bf16x8*)(rB[t4] + co);
            }
            #pragma unroll
            for (int mt = 0; mt < 4; ++mt)
                #pragma unroll
                for (int nt = 0; nt < 4; ++nt)
                    acc[mt][nt] = __builtin_amdgcn_mfma_f32_16x16x32_bf16(
                        af[mt], bfr[nt], acc[mt][nt], 0, 0, 0);
        }
    }

    // ---- stats epilogue via LDS (low VGPR). C/D layout: col=l15, row=q*4+r.
    __syncthreads();                       // all tile ds_reads done
    bf16_t* sh = (bf16_t*)smem;            // [128][130] bf16 = 33280 B
    float*  su = (float*)(smem + 33280);   // u[n0..n0+127]          512 B
    float*  sp = (float*)(smem + 33792);   // [256][3] partials     3072 B

    if (tid < 128) su[tid] = u[n0 + tid];
    float bias4[4];
    #pragma unroll
    for (int nt = 0; nt < 4; ++nt) bias4[nt] = bias[n0 + wc * 64 + nt * 16 + l15];

    #pragma unroll
    for (int mt = 0; mt < 4; ++mt)
        #pragma unroll
        for (int nt = 0; nt < 4; ++nt)
            #pragma unroll
            for (int r = 0; r < 4; ++r) {
                const int rowl = wr * 64 + mt * 16 + q * 4 + r;
                const int coll = wc * 64 + nt * 16 + l15;
                sh[rowl * 130 + coll] = (bf16_t)gelu_fast(acc[mt][nt][r] + bias4[nt]);
            }
    __syncthreads();

    // phase 2: thread = (row, half); reduce 64 cols each
    {
        const int rowl = tid >> 1, half = tid & 1;
        const bf16_t* hp = sh + rowl * 130 + half * 64;
        const float*  up = su + half * 64;
        float s1 = 0.f, s2 = 0.f, dd = 0.f;
        #pragma unroll
        for (int c = 0; c < 64; ++c) {
            const float v = (float)hp[c];
            s1 += v; s2 += v * v; dd += v * up[c];
        }
        sp[tid * 3 + 0] = s1; sp[tid * 3 + 1] = s2; sp[tid * 3 + 2] = dd;
    }
    __syncthreads();
    if (tid < 128) {
        const float* p0 = sp + (2 * tid) * 3;
        const float* p1 = sp + (2 * tid + 1) * 3;
        const size_t idx = (size_t)bx * 32768 + (m0 + tid);
        pS1[idx] = p0[0] + p1[0];
        pS2[idx] = p0[1] + p1[1];
        pD[idx]  = p0[2] + p1[2];
    }
}

// ---------------------------------------------------------------------------
// out_scores: out[t*8+k] = rstd*(D - mu*Gw) + Bw   (32768 threads)
// ---------------------------------------------------------------------------
__global__ __launch_bounds__(256) void out_scores(
        const float* __restrict__ pS1, const float* __restrict__ pS2,
        const float* __restrict__ pD,  const float* __restrict__ gwbw,
        float* __restrict__ out) {
    const int t = blockIdx.x * 256 + threadIdx.x;   // 32768 exactly
    float s1 = 0.f, s2 = 0.f, d = 0.f;
    #pragma unroll
    for (int nt = 0; nt < 12; ++nt) {
        const size_t idx = (size_t)nt * 32768 + t;
        s1 += pS1[idx]; s2 += pS2[idx]; d += pD[idx];
    }
    const float mu   = s1 * (1.0f / 1536.0f);
    const float var  = s2 * (1.0f / 1536.0f) - mu * mu;
    const float rstd = rsqrtf(var + 1e-12f);
    const float v = rstd * (d - mu * gwbw[0]) + gwbw[1];
    const float4 f = make_float4(v, v, v, v);
    float4* o = (float4*)(out + (size_t)t * 8);
    o[0] = f; o[1] = f;
}

// ---------------------------------------------------------------------------
extern "C" void kernel_launch(void* const* d_in, const int* in_sizes, int n_in,
                              void* d_out, int out_size, void* d_ws, size_t ws_size,
                              hipStream_t stream) {
    const float* E   = (const float*)d_in[0];
    const float* W1  = (const float*)d_in[1];
    const float* b1  = (const float*)d_in[2];
    const float* lng = (const float*)d_in[3];
    const float* lnb = (const float*)d_in[4];
    const float* W2  = (const float*)d_in[5];
    const float* b2  = (const float*)d_in[6];
    float* out = (float*)d_out;

    char* w = (char*)d_ws;
    auto carve = [&](size_t bytes) {
        void* p = (void*)w;
        w += (bytes + 255) & ~(size_t)255;
        return p;
    };
    bf16_t* W1t   = (bf16_t*)carve((size_t)1536 * 768 * 2);    //  2.4 MB
    bf16_t* Ebf   = (bf16_t*)carve((size_t)32768 * 768 * 2);   // 50.3 MB
    float*  u     = (float*)carve(1536 * 4);
    float*  gwbw  = (float*)carve(256);
    // Union region: hpart (12.6 MB, written by prep_duo, dead after
    // own_lnlog) overlaps pS1/pS2/pD (4.7 MB, first written by gemm1p,
    // which runs after own_lnlog) — disjoint lifetimes.
    char*   unionr = (char*)carve((size_t)4 * 512 * 1536 * 4); // 12.6 MB
    float*  hpart = (float*)unionr;
    float*  pS1   = (float*)unionr;
    float*  pS2   = (float*)(unionr + (size_t)12 * 32768 * 4);
    float*  pD    = (float*)(unionr + (size_t)24 * 32768 * 4);

    // 1) prep: W1 transpose + own-row k-partials + E->bf16 (fused grid)
    prep_duo<<<13344, 256, 0, stream>>>(E, W1, W1t, hpart, Ebf);
    // 2) own rows: gelu+LN+logits+softmax/argmax; block 511 -> u/Gw/Bw
    own_lnlog<<<512, 512, 0, stream>>>(hpart, b1, lng, lnb, W2, b2,
                                       out, u, gwbw);
    // 3) fused GEMM, both operands bf16 via async DMA
    gemm1p<<<dim3(12, 256), 256, 0, stream>>>(Ebf, W1t, b1, u, pS1, pS2, pD);
    // 4) combine partials -> output 0
    out_scores<<<128, 256, 0, stream>>>(pS1, pS2, pD, gwbw, out);
}